// Round 15
// baseline (1154.628 us; speedup 1.0000x reference)
//
#include <hip/hip_runtime.h>
#include <hip/hip_bf16.h>
#include <hip/hip_fp16.h>

// GCN 2-layer: out = Ahat * relu(Ahat*(X W1)+b1) * W2 + b2
// Round 15: CSR-free aggregation via per-bucket LDS accumulators.
//  - bucket sort by dst>>9 (passA/col_scan/passB) kept from R13.
//  - bucket_csr replaced by bucket_cnt (hist -> dinv only); row_ptr/csr_src
//    deleted.
//  - aggregate: block=(bucket, feature-quarter); LDS acc[512][16] fp32
//    (17-stride pad); 4 lanes/edge x half4 -> 16 edges per gather instr;
//    4 ds_add_f32 per edge; epilogue relu(dinv*(acc+self)+b1) coalesced.
//    VMEM instrs: E/4 gather + E/16 bedges (R13: E/4 + E/4 csr_src).
//  - R14's perm + replicated hists reverted (regression).

#define N_FEAT_IN 64
#define B2SHIFT 9        // 512 dst nodes per coarse bucket
#define CHUNK 4096       // edges per block in pass A/B

struct alignas(8) half4 { __half2 lo, hi; };

// ---- pass A: per-chunk bucket histogram (LDS, no global atomics) ----
__global__ __launch_bounds__(1024) void passA_hist(const int* __restrict__ dst,
                                                   int* __restrict__ H, int E) {
    __shared__ int h[256];
    int t = threadIdx.x;
    if (t < 256) h[t] = 0;
    __syncthreads();
    int base = blockIdx.x * CHUNK;
    int end = min(base + CHUNK, E);
    for (int i = base + t; i < end; i += 1024)
        atomicAdd(&h[dst[i] >> B2SHIFT], 1);
    __syncthreads();
    if (t < 256) H[blockIdx.x * 256 + t] = h[t];
}

// ---- col_scan_a: one block per column; exclusive scan over NR rows ----
__global__ __launch_bounds__(512) void col_scan_a(int* __restrict__ H,
                                                  int* __restrict__ ctot, int NR) {
    __shared__ int s[512];
    int b = blockIdx.x;
    int t = threadIdx.x;
    int v = (t < NR) ? H[t * 256 + b] : 0;
    s[t] = v;
    __syncthreads();
    for (int off = 1; off < 512; off <<= 1) {
        int a = (t >= off) ? s[t - off] : 0;
        __syncthreads();
        s[t] += a;
        __syncthreads();
    }
    if (t < NR) H[t * 256 + b] = s[t] - v;
    if (t == 511) ctot[b] = s[511];
}

// ---- col_scan_b: scan column totals -> per-bucket bases ----
__global__ __launch_bounds__(256) void col_scan_b(const int* __restrict__ ctot,
                                                  int* __restrict__ cbase,
                                                  int* __restrict__ bbase,
                                                  int NB, int E) {
    __shared__ int s[256];
    int t = threadIdx.x;
    int v = ctot[t];
    s[t] = v;
    __syncthreads();
    for (int off = 1; off < 256; off <<= 1) {
        int a = (t >= off) ? s[t - off] : 0;
        __syncthreads();
        s[t] += a;
        __syncthreads();
    }
    int e = s[t] - v;
    cbase[t] = e;
    if (t < NB) bbase[t] = e;
    if (t == 0) bbase[NB] = E;
}

// ---- pass B: place packed edges into private per-chunk runs ----
__global__ __launch_bounds__(1024) void passB_place(const int* __restrict__ src,
                                                    const int* __restrict__ dst,
                                                    const int* __restrict__ H,
                                                    const int* __restrict__ cbase,
                                                    unsigned* __restrict__ bedges, int E) {
    __shared__ int cur[256];
    int t = threadIdx.x;
    if (t < 256) cur[t] = H[blockIdx.x * 256 + t] + cbase[t];
    __syncthreads();
    int base = blockIdx.x * CHUNK;
    int end = min(base + CHUNK, E);
    for (int i = base + t; i < end; i += 1024) {
        int d = dst[i];
        int p = atomicAdd(&cur[d >> B2SHIFT], 1);  // LDS atomic
        bedges[p] = ((unsigned)src[i] << B2SHIFT) | (unsigned)(d & 511);
    }
}

// ---- bucket_cnt: per-bucket 512-bin hist -> dinv (coalesced) ----
__global__ __launch_bounds__(1024) void bucket_cnt(const int* __restrict__ bbase,
                                                   const unsigned* __restrict__ bedges,
                                                   float* __restrict__ dinv, int n) {
    __shared__ int lh[512];
    int t = threadIdx.x;
    if (t < 512) lh[t] = 0;
    __syncthreads();
    int b = blockIdx.x;
    int beg = bbase[b], end = bbase[b + 1];
    for (int i = beg + t; i < end; i += 1024)
        atomicAdd(&lh[bedges[i] & 511], 1);
    __syncthreads();
    if (t < 512) {
        int d = (b << B2SHIFT) + t;
        if (d < n) dinv[d] = rsqrtf((float)lh[t] + 1.0f);
    }
}

// ---- GEMM layer1: xs1[n,64] fp16 = half( dinv[row] * (X W1) ) ----
__global__ __launch_bounds__(256) void gemm64(const float* __restrict__ A,
                                              const float* __restrict__ W,
                                              const float* __restrict__ dinv,
                                              __half* __restrict__ outh, int n) {
    constexpr int K = 64, FO = 64, CPT = 16;
    __shared__ float As[64][K + 4];
    __shared__ float Ws[K][FO];

    const int t = threadIdx.x;
    const int r0 = blockIdx.x * 64;

    for (int i = t; i < K * FO / 4; i += 256) {
        int k = i / (FO / 4);
        int c4 = (i % (FO / 4)) * 4;
        *(float4*)&Ws[k][c4] = *(const float4*)&W[k * FO + c4];
    }
    for (int i = t; i < 1024; i += 256) {
        int row = i / 16;
        int c4 = (i % 16) * 4;
        int g = r0 + row;
        float4 v = make_float4(0.f, 0.f, 0.f, 0.f);
        if (g < n) v = *(const float4*)&A[(size_t)g * K + c4];
        *(float4*)&As[row][c4] = v;
    }
    __syncthreads();

    const int row = t >> 2;
    const int c0 = (t & 3) * CPT;
    float acc[CPT];
#pragma unroll
    for (int j = 0; j < CPT; ++j) acc[j] = 0.f;
#pragma unroll
    for (int k = 0; k < K; ++k) {
        float xv = As[row][k];
#pragma unroll
        for (int j = 0; j < CPT; ++j) acc[j] = fmaf(xv, Ws[k][c0 + j], acc[j]);
    }

    int g = r0 + row;
    if (g < n) {
        float sc = dinv[g];
#pragma unroll
        for (int j4 = 0; j4 < CPT; j4 += 4) {
            half4 h;
            h.lo = __floats2half2_rn(acc[j4] * sc, acc[j4 + 1] * sc);
            h.hi = __floats2half2_rn(acc[j4 + 2] * sc, acc[j4 + 3] * sc);
            *(half4*)&outh[(size_t)g * FO + c0 + j4] = h;
        }
    }
}

// ---- agg64_lds: block=(bucket, quarter); LDS fp32 accumulators ----
// t = relu(dinv*(acc+self) + b1) -> fp16 th.
__global__ __launch_bounds__(512) void agg64_lds(const int* __restrict__ bbase,
                                                 const unsigned* __restrict__ bedges,
                                                 const float* __restrict__ dinv,
                                                 const __half* __restrict__ xs1,
                                                 const float* __restrict__ b1,
                                                 __half* __restrict__ th, int n) {
    __shared__ float acc[512 * 17];   // [row][16feat], stride 17 (34KB)
    int t = threadIdx.x;
    int b = blockIdx.x;
    int fb = blockIdx.y * 16;         // feature quarter base
    for (int i = t; i < 512 * 17; i += 512) acc[i] = 0.f;
    __syncthreads();

    int beg = bbase[b], end = bbase[b + 1];
    int c4 = (t & 3) * 4;             // feature offset within quarter
    int eg = t >> 2;                  // edge group 0..127

    for (int i = beg + eg; i < end; i += 512) {
        unsigned v[4];
        bool ok[4];
#pragma unroll
        for (int k = 0; k < 4; ++k) {
            int j = i + k * 128;
            ok[k] = j < end;
            v[k] = bedges[min(j, end - 1)];
        }
        half4 h[4];
#pragma unroll
        for (int k = 0; k < 4; ++k)
            h[k] = *(const half4*)&xs1[(size_t)(v[k] >> B2SHIFT) * 64 + fb + c4];
#pragma unroll
        for (int k = 0; k < 4; ++k) {
            if (ok[k]) {
                float* a = &acc[(int)(v[k] & 511) * 17 + c4];
                float2 lo = __half22float2(h[k].lo), hi = __half22float2(h[k].hi);
                atomicAdd(&a[0], lo.x);
                atomicAdd(&a[1], lo.y);
                atomicAdd(&a[2], hi.x);
                atomicAdd(&a[3], hi.y);
            }
        }
    }
    __syncthreads();

    // epilogue: thread t = local row
    int d = (b << B2SHIFT) + t;
    if (d < n) {
        float di = dinv[d];
        half4 h[4];
#pragma unroll
        for (int k = 0; k < 4; ++k)
            h[k] = *(const half4*)&xs1[(size_t)d * 64 + fb + 4 * k];
        half4 o[4];
#pragma unroll
        for (int k = 0; k < 4; ++k) {
            float2 lo = __half22float2(h[k].lo), hi = __half22float2(h[k].hi);
            float f0 = acc[t * 17 + 4 * k + 0] + lo.x;
            float f1 = acc[t * 17 + 4 * k + 1] + lo.y;
            float f2 = acc[t * 17 + 4 * k + 2] + hi.x;
            float f3 = acc[t * 17 + 4 * k + 3] + hi.y;
            f0 = fmaxf(fmaf(di, f0, b1[fb + 4 * k + 0]), 0.f);
            f1 = fmaxf(fmaf(di, f1, b1[fb + 4 * k + 1]), 0.f);
            f2 = fmaxf(fmaf(di, f2, b1[fb + 4 * k + 2]), 0.f);
            f3 = fmaxf(fmaf(di, f3, b1[fb + 4 * k + 3]), 0.f);
            o[k].lo = __floats2half2_rn(f0, f1);
            o[k].hi = __floats2half2_rn(f2, f3);
        }
#pragma unroll
        for (int k = 0; k < 4; ++k)
            *(half4*)&th[(size_t)d * 64 + fb + 4 * k] = o[k];
    }
}

// ---- gemm32h: xs2[n,32] fp16 = half( dinv[row] * (t[n,64] W2) ) ----
__global__ __launch_bounds__(256) void gemm32h(const __half* __restrict__ Ah,
                                               const float* __restrict__ W,
                                               const float* __restrict__ dinv,
                                               __half* __restrict__ outh, int n) {
    constexpr int K = 64, FO = 32, CPT = 8;
    __shared__ float As[64][K + 4];
    __shared__ float Ws[K][FO];

    const int t = threadIdx.x;
    const int r0 = blockIdx.x * 64;

    for (int i = t; i < K * FO / 4; i += 256) {
        int k = i / (FO / 4);
        int c4 = (i % (FO / 4)) * 4;
        *(float4*)&Ws[k][c4] = *(const float4*)&W[k * FO + c4];
    }
    for (int i = t; i < 1024; i += 256) {
        int row = i / 16;
        int c4 = (i % 16) * 4;
        int g = r0 + row;
        float4 v = make_float4(0.f, 0.f, 0.f, 0.f);
        if (g < n) {
            half4 hv = *(const half4*)&Ah[(size_t)g * K + c4];
            float2 lo = __half22float2(hv.lo), hi = __half22float2(hv.hi);
            v = make_float4(lo.x, lo.y, hi.x, hi.y);
        }
        *(float4*)&As[row][c4] = v;
    }
    __syncthreads();

    const int row = t >> 2;
    const int c0 = (t & 3) * CPT;
    float acc[CPT];
#pragma unroll
    for (int j = 0; j < CPT; ++j) acc[j] = 0.f;
#pragma unroll
    for (int k = 0; k < K; ++k) {
        float xv = As[row][k];
#pragma unroll
        for (int j = 0; j < CPT; ++j) acc[j] = fmaf(xv, Ws[k][c0 + j], acc[j]);
    }

    int g = r0 + row;
    if (g < n) {
        float sc = dinv[g];
#pragma unroll
        for (int j4 = 0; j4 < CPT; j4 += 4) {
            half4 h;
            h.lo = __floats2half2_rn(acc[j4] * sc, acc[j4 + 1] * sc);
            h.hi = __floats2half2_rn(acc[j4 + 2] * sc, acc[j4 + 3] * sc);
            *(half4*)&outh[(size_t)g * FO + c0 + j4] = h;
        }
    }
}

// ---- agg32_lds: block=(bucket, half); out = dinv*(acc+self) + b2 (fp32) ----
__global__ __launch_bounds__(512) void agg32_lds(const int* __restrict__ bbase,
                                                 const unsigned* __restrict__ bedges,
                                                 const float* __restrict__ dinv,
                                                 const __half* __restrict__ xs2,
                                                 const float* __restrict__ b2,
                                                 float* __restrict__ out, int n) {
    __shared__ float acc[512 * 17];   // [row][16feat], stride 17 (34KB)
    int t = threadIdx.x;
    int b = blockIdx.x;
    int fb = blockIdx.y * 16;         // feature half base
    for (int i = t; i < 512 * 17; i += 512) acc[i] = 0.f;
    __syncthreads();

    int beg = bbase[b], end = bbase[b + 1];
    int c4 = (t & 3) * 4;
    int eg = t >> 2;

    for (int i = beg + eg; i < end; i += 512) {
        unsigned v[4];
        bool ok[4];
#pragma unroll
        for (int k = 0; k < 4; ++k) {
            int j = i + k * 128;
            ok[k] = j < end;
            v[k] = bedges[min(j, end - 1)];
        }
        half4 h[4];
#pragma unroll
        for (int k = 0; k < 4; ++k)
            h[k] = *(const half4*)&xs2[(size_t)(v[k] >> B2SHIFT) * 32 + fb + c4];
#pragma unroll
        for (int k = 0; k < 4; ++k) {
            if (ok[k]) {
                float* a = &acc[(int)(v[k] & 511) * 17 + c4];
                float2 lo = __half22float2(h[k].lo), hi = __half22float2(h[k].hi);
                atomicAdd(&a[0], lo.x);
                atomicAdd(&a[1], lo.y);
                atomicAdd(&a[2], hi.x);
                atomicAdd(&a[3], hi.y);
            }
        }
    }
    __syncthreads();

    int d = (b << B2SHIFT) + t;
    if (d < n) {
        float di = dinv[d];
        half4 h[4];
#pragma unroll
        for (int k = 0; k < 4; ++k)
            h[k] = *(const half4*)&xs2[(size_t)d * 32 + fb + 4 * k];
#pragma unroll
        for (int k = 0; k < 4; ++k) {
            float2 lo = __half22float2(h[k].lo), hi = __half22float2(h[k].hi);
            float4 r;
            r.x = fmaf(di, acc[t * 17 + 4 * k + 0] + lo.x, b2[fb + 4 * k + 0]);
            r.y = fmaf(di, acc[t * 17 + 4 * k + 1] + lo.y, b2[fb + 4 * k + 1]);
            r.z = fmaf(di, acc[t * 17 + 4 * k + 2] + hi.x, b2[fb + 4 * k + 2]);
            r.w = fmaf(di, acc[t * 17 + 4 * k + 3] + hi.y, b2[fb + 4 * k + 3]);
            *(float4*)&out[(size_t)d * 32 + fb + 4 * k] = r;
        }
    }
}

extern "C" void kernel_launch(void* const* d_in, const int* in_sizes, int n_in,
                              void* d_out, int out_size, void* d_ws, size_t ws_size,
                              hipStream_t stream) {
    const float* x  = (const float*)d_in[0];   // [n, 64]
    const int*   ei = (const int*)d_in[1];     // [2, E]
    const float* W1 = (const float*)d_in[2];   // [64, 64]
    const float* b1 = (const float*)d_in[3];   // [64]
    const float* W2 = (const float*)d_in[4];   // [64, 32]
    const float* b2 = (const float*)d_in[5];   // [32]
    float* out = (float*)d_out;                // [n, 32]

    const int n = in_sizes[0] / N_FEAT_IN;     // 100000
    const int E = in_sizes[1] / 2;             // 1600000
    const int* srcI = ei;
    const int* dstI = ei + E;

    const int NB = (n + 511) >> B2SHIFT;       // 196 coarse buckets
    const int NR = (E + CHUNK - 1) / CHUNK;    // 391 chunks

    // workspace layout (256B aligned)
    char* ws = (char*)d_ws;
    size_t off = 0;
    auto alloc = [&](size_t bytes) {
        void* p = ws + off;
        off += (bytes + 255) & ~(size_t)255;
        return p;
    };
    float*    dinv   = (float*)alloc((size_t)n * 4);
    int*      bbase  = (int*)alloc((size_t)(NB + 1) * 4);
    int*      ctot   = (int*)alloc((size_t)256 * 4);
    int*      cbase  = (int*)alloc((size_t)256 * 4);
    int*      H      = (int*)alloc((size_t)NR * 256 * 4);   // ~400KB
    unsigned* bedges = (unsigned*)alloc((size_t)E * 4);
    __half*   xs1    = (__half*)alloc((size_t)n * 64 * 2);
    __half*   th     = (__half*)alloc((size_t)n * 64 * 2);
    __half*   xs2    = (__half*)alloc((size_t)n * 32 * 2);

    // 1) atomic-free bucket sort by dst>>9
    passA_hist<<<NR, 1024, 0, stream>>>(dstI, H, E);
    col_scan_a<<<256, 512, 0, stream>>>(H, ctot, NR);
    col_scan_b<<<1, 256, 0, stream>>>(ctot, cbase, bbase, NB, E);
    passB_place<<<NR, 1024, 0, stream>>>(srcI, dstI, H, cbase, bedges, E);

    // 2) per-node degree -> dinv
    bucket_cnt<<<NB, 1024, 0, stream>>>(bbase, bedges, dinv, n);

    // 3) layer 1 GEMM: xs1 = half(dinv .* (X W1))
    gemm64<<<(n + 63) / 64, 256, 0, stream>>>(x, W1, dinv, xs1, n);

    // 4) layer-1 aggregate (LDS accumulators): t = relu(dinv*(agg+self)+b1)
    agg64_lds<<<dim3(NB, 4), 512, 0, stream>>>(bbase, bedges, dinv, xs1, b1, th, n);

    // 5) layer-2 transform: xs2 = half(dinv .* (t W2))
    gemm32h<<<(n + 63) / 64, 256, 0, stream>>>(th, W2, dinv, xs2, n);

    // 6) layer-2 aggregate -> out
    agg32_lds<<<dim3(NB, 2), 512, 0, stream>>>(bbase, bedges, dinv, xs2, b2, out, n);
}